// Round 2
// baseline (541.705 us; speedup 1.0000x reference)
//
#include <hip/hip_runtime.h>
#include <hip/hip_bf16.h>
#include <math.h>
#include <stdint.h>

#define N_S 512
#define D_S 512
#define C_S 100000
#define SCALEF 64.0f
#define EPSV 1e-7f
// cos(0.5), sin(0.5), cos(pi-0.5), sin(pi-0.5)*0.5
#define COS_M 0.8775825618903728f
#define SIN_M 0.4794255386042030f
#define TH_C (-0.8775825618903728f)
#define MM_C 0.2397127693021015f

#define BM 128
#define BC 128
#define BK 64
#define NCB ((C_S + BC - 1) / BC)   // 782
#define PPR (NCB * 2)               // 1564 partials per row

typedef __attribute__((ext_vector_type(8))) short bf16x8;
typedef __attribute__((ext_vector_type(4))) float f32x4;

__device__ __forceinline__ short f2bf(float f) {
    uint32_t u = __builtin_bit_cast(uint32_t, f);
    u += 0x7FFFu + ((u >> 16) & 1u);   // round-to-nearest-even
    return (short)(u >> 16);
}

// ---------------- kernel 1: normalize x rows -> bf16 ----------------
__global__ void xnorm_k(const float* __restrict__ x, short* __restrict__ xb) {
    int row = blockIdx.x;          // 512 rows
    int tid = threadIdx.x;         // 256 threads
    float2 v = *(const float2*)(x + (size_t)row * D_S + tid * 2);
    float ss = v.x * v.x + v.y * v.y;
    #pragma unroll
    for (int m = 1; m < 64; m <<= 1) ss += __shfl_xor(ss, m);
    __shared__ float sred[4];
    if ((tid & 63) == 0) sred[tid >> 6] = ss;
    __syncthreads();
    float tot = sred[0] + sred[1] + sred[2] + sred[3];
    float scale = 1.0f / fmaxf(sqrtf(tot), 1e-12f);
    short2 o;
    o.x = f2bf(v.x * scale);
    o.y = f2bf(v.y * scale);
    *(short2*)(xb + (size_t)row * D_S + tid * 2) = o;
}

// ---------------- kernel 2: w row inverse norms ----------------
__global__ void wnorm_k(const float* __restrict__ w, float* __restrict__ winv) {
    int c = blockIdx.x * 4 + (threadIdx.x >> 6);   // 4 waves, one row each
    int lane = threadIdx.x & 63;
    const float4* p = (const float4*)(w + (size_t)c * D_S);
    float4 a = p[lane];
    float4 b = p[lane + 64];
    float ss = a.x * a.x + a.y * a.y + a.z * a.z + a.w * a.w
             + b.x * b.x + b.y * b.y + b.z * b.z + b.w * b.w;
    #pragma unroll
    for (int m = 1; m < 64; m <<= 1) ss += __shfl_xor(ss, m);
    if (lane == 0) winv[c] = 1.0f / fmaxf(sqrtf(ss), 1e-12f);
}

// ---------------- kernel 3: GEMM + ArcFace + softmax partials ----------------
__global__ void gemm_arc_k(const short* __restrict__ xb,
                           const float* __restrict__ w,
                           const float* __restrict__ winv,
                           const int* __restrict__ tgt,
                           float* __restrict__ partM,
                           float* __restrict__ partS,
                           float* __restrict__ tgtlogit) {
    __shared__ short Alds[BM * BK];   // [m][k] row-major, 16 KB
    __shared__ short Blds[BC * BK];   // [c][k] row-major, 16 KB
    __shared__ int tgts[BM];

    int rb = blockIdx.x;              // 0..3 (row blocks, fast-varying for L3 reuse of w)
    int cb = blockIdx.y;              // 0..781
    int row0 = rb * BM;
    int col0 = cb * BC;
    int tid = threadIdx.x;            // 256
    int wid = tid >> 6;
    int lane = tid & 63;
    int wm = wid >> 1;                // wave rows: wm*64
    int wn = wid & 1;                 // wave cols: wn*64

    if (tid < BM) tgts[tid] = tgt[row0 + tid];

    f32x4 acc[4][4] = {};

    // B staging assignment: thread pair per tile row c, 32 k each
    int bc_r = tid >> 1;              // 0..127
    int bkh  = (tid & 1) * 32;        // k half offset
    int cg   = col0 + bc_r;
    int csrc = cg < C_S ? cg : C_S - 1;
    float wi = winv[csrc];

    for (int kt = 0; kt < D_S; kt += BK) {
        __syncthreads();
        // ---- stage A (bf16, already normalized) ----
        #pragma unroll
        for (int p = 0; p < 4; p++) {
            int flat = p * 4096 + tid * 16;        // byte offset into Alds
            int m  = flat >> 7;                    // tile row
            int kb = (flat & 127) >> 1;            // k element offset
            *(int4*)((char*)Alds + flat) =
                *(const int4*)(xb + (size_t)(row0 + m) * D_S + kt + kb);
        }
        // ---- stage B: f32 load, scale by invnorm, convert, write LDS ----
        {
            const float4* wp = (const float4*)(w + (size_t)csrc * D_S + kt + bkh);
            char* bdst = (char*)Blds + bc_r * 128 + bkh * 2;
            #pragma unroll
            for (int j = 0; j < 8; j++) {
                float4 v = wp[j];
                short4 o;
                o.x = f2bf(v.x * wi);
                o.y = f2bf(v.y * wi);
                o.z = f2bf(v.z * wi);
                o.w = f2bf(v.w * wi);
                *(short4*)(bdst + j * 8) = o;
            }
        }
        __syncthreads();
        // ---- MFMA over the staged K chunk ----
        #pragma unroll
        for (int kk = 0; kk < BK; kk += 32) {
            int krow = kk + ((lane >> 4) << 3);
            bf16x8 af[4], bfr[4];
            #pragma unroll
            for (int mr = 0; mr < 4; mr++) {
                int r = wm * 64 + mr * 16 + (lane & 15);
                af[mr] = *(const bf16x8*)((char*)Alds + r * 128 + krow * 2);
            }
            #pragma unroll
            for (int nc = 0; nc < 4; nc++) {
                int c = wn * 64 + nc * 16 + (lane & 15);
                bfr[nc] = *(const bf16x8*)((char*)Blds + c * 128 + krow * 2);
            }
            #pragma unroll
            for (int mr = 0; mr < 4; mr++)
                #pragma unroll
                for (int nc = 0; nc < 4; nc++)
                    acc[mr][nc] = __builtin_amdgcn_mfma_f32_16x16x32_bf16(
                        af[mr], bfr[nc], acc[mr][nc], 0, 0, 0);
        }
    }

    // ---- epilogue: ArcFace transform + per-row online softmax partials ----
    int lg  = lane >> 4;
    int l15 = lane & 15;
    #pragma unroll
    for (int mr = 0; mr < 4; mr++) {
        #pragma unroll
        for (int r = 0; r < 4; r++) {
            int row_l = wm * 64 + mr * 16 + lg * 4 + r;
            int row_g = row0 + row_l;
            int tg = tgts[row_l];
            float lv[4];
            #pragma unroll
            for (int nc = 0; nc < 4; nc++) {
                int c_g = col0 + wn * 64 + nc * 16 + l15;
                float cosv = acc[mr][nc][r];
                cosv = fminf(fmaxf(cosv, -1.0f + EPSV), 1.0f - EPSV);
                float lo = cosv * SCALEF;
                if (c_g == tg) {
                    float s2 = 1.0f - cosv * cosv;
                    s2 = fminf(fmaxf(s2, -1.0f + EPSV), 1.0f - EPSV);
                    float sine = sqrtf(s2);
                    float phi = cosv * COS_M - sine * SIN_M;
                    if (!(cosv > TH_C)) phi = cosv - MM_C;
                    lo = phi * SCALEF;
                    tgtlogit[row_g] = lo;
                }
                if (c_g >= C_S) lo = -INFINITY;
                lv[nc] = lo;
            }
            float m = fmaxf(fmaxf(lv[0], lv[1]), fmaxf(lv[2], lv[3]));
            #pragma unroll
            for (int d = 1; d < 16; d <<= 1) m = fmaxf(m, __shfl_xor(m, d));
            float s = 0.0f;
            #pragma unroll
            for (int nc = 0; nc < 4; nc++)
                if (lv[nc] > -INFINITY) s += __expf(lv[nc] - m);
            #pragma unroll
            for (int d = 1; d < 16; d <<= 1) s += __shfl_xor(s, d);
            if (l15 == 0) {
                int pi = row_g * PPR + cb * 2 + wn;
                partM[pi] = m;
                partS[pi] = s;
            }
        }
    }
}

// ---------------- kernel 4: per-row merge of partials -> nll ----------------
__global__ void reduce_k(const float* __restrict__ partM,
                         const float* __restrict__ partS,
                         const float* __restrict__ tgtlogit,
                         float* __restrict__ nll) {
    int row = blockIdx.x;   // 512
    int tid = threadIdx.x;  // 256
    float m = -INFINITY, s = 0.0f;
    for (int p = tid; p < PPR; p += 256) {
        float mp = partM[(size_t)row * PPR + p];
        float sp = partS[(size_t)row * PPR + p];
        if (sp > 0.0f) {
            float mn = fmaxf(m, mp);
            s = s * __expf(m - mn) + sp * __expf(mp - mn);
            m = mn;
        }
    }
    __shared__ float rm[256], rs[256];
    rm[tid] = m; rs[tid] = s;
    __syncthreads();
    for (int h = 128; h > 0; h >>= 1) {
        if (tid < h) {
            float mp = rm[tid + h], sp = rs[tid + h];
            if (sp > 0.0f) {
                float mn = fmaxf(rm[tid], mp);
                rs[tid] = rs[tid] * __expf(rm[tid] - mn) + sp * __expf(mp - mn);
                rm[tid] = mn;
            }
        }
        __syncthreads();
    }
    if (tid == 0) nll[row] = (rm[0] + logf(rs[0])) - tgtlogit[row];
}

// ---------------- kernel 5: mean ----------------
__global__ void finalize_k(const float* __restrict__ nll, float* __restrict__ out) {
    int tid = threadIdx.x;  // 256
    float v = nll[tid] + nll[tid + 256];
    #pragma unroll
    for (int d = 1; d < 64; d <<= 1) v += __shfl_xor(v, d);
    __shared__ float sr[4];
    if ((tid & 63) == 0) sr[tid >> 6] = v;
    __syncthreads();
    if (tid == 0) out[0] = (sr[0] + sr[1] + sr[2] + sr[3]) * (1.0f / 512.0f);
}

extern "C" void kernel_launch(void* const* d_in, const int* in_sizes, int n_in,
                              void* d_out, int out_size, void* d_ws, size_t ws_size,
                              hipStream_t stream) {
    const float* x   = (const float*)d_in[0];
    const int*   tgt = (const int*)d_in[1];
    const float* w   = (const float*)d_in[2];
    float* out = (float*)d_out;
    char* ws = (char*)d_ws;

    short* xb   = (short*)(ws + 0);            // 512*512*2   = 524288
    float* winv = (float*)(ws + 524288);       // 100000*4    = 400000
    float* tgl  = (float*)(ws + 924288);       // 512*4
    float* nll  = (float*)(ws + 926336);       // 512*4
    float* pM   = (float*)(ws + 928384);       // 512*1564*4  = 3203072
    float* pS   = (float*)(ws + 4131456);      // 3203072 (end ~7.3 MB)

    xnorm_k<<<512, 256, 0, stream>>>(x, xb);
    wnorm_k<<<C_S / 4, 256, 0, stream>>>(w, winv);
    dim3 g(4, NCB);
    gemm_arc_k<<<g, 256, 0, stream>>>(xb, w, winv, tgt, pM, pS, tgl);
    reduce_k<<<512, 256, 0, stream>>>(pM, pS, tgl, nll);
    finalize_k<<<1, 256, 0, stream>>>(nll, out);
}

// Round 4
// 394.511 us; speedup vs baseline: 1.3731x; 1.3731x over previous
//
#include <hip/hip_runtime.h>
#include <hip/hip_bf16.h>
#include <math.h>
#include <stdint.h>

#define N_S 512
#define D_S 512
#define C_S 100000
#define SCALEF 64.0f
#define EPSV 1e-7f
// cos(0.5), sin(0.5), cos(pi-0.5), sin(pi-0.5)*0.5
#define COS_M 0.8775825618903728f
#define SIN_M 0.4794255386042030f
#define TH_C (-0.8775825618903728f)
#define MM_C 0.2397127693021015f

#define BM 128
#define BC 128
#define BK 64
#define NCB ((C_S + BC - 1) / BC)   // 782
#define PPR (NCB * 2)               // 1564 partials per row
#define NWG (4 * NCB)               // 3128 (divisible by 8)
#define CHUNK (NWG / 8)             // 391

typedef __attribute__((ext_vector_type(8))) short bf16x8;
typedef __attribute__((ext_vector_type(4))) float f32x4;

#define GLOAD_LDS16(g, l)                                                     \
    __builtin_amdgcn_global_load_lds(                                         \
        (const __attribute__((address_space(1))) unsigned int*)(g),           \
        (__attribute__((address_space(3))) unsigned int*)(l), 16, 0, 0)

__device__ __forceinline__ short f2bf(float f) {
    uint32_t u = __builtin_bit_cast(uint32_t, f);
    u += 0x7FFFu + ((u >> 16) & 1u);   // round-to-nearest-even
    return (short)(u >> 16);
}

// ---------------- kernel 1: normalize x rows -> bf16 ----------------
__global__ void xnorm_k(const float* __restrict__ x, short* __restrict__ xb) {
    int row = blockIdx.x;          // 512 rows
    int tid = threadIdx.x;         // 256 threads
    float2 v = *(const float2*)(x + (size_t)row * D_S + tid * 2);
    float ss = v.x * v.x + v.y * v.y;
    #pragma unroll
    for (int m = 1; m < 64; m <<= 1) ss += __shfl_xor(ss, m);
    __shared__ float sred[4];
    if ((tid & 63) == 0) sred[tid >> 6] = ss;
    __syncthreads();
    float tot = sred[0] + sred[1] + sred[2] + sred[3];
    float scale = 1.0f / fmaxf(sqrtf(tot), 1e-12f);
    short2 o;
    o.x = f2bf(v.x * scale);
    o.y = f2bf(v.y * scale);
    *(short2*)(xb + (size_t)row * D_S + tid * 2) = o;
}

// ---------------- kernel 2 (fast): fused w norm + bf16 convert ----------------
__global__ void wnc_k(const float* __restrict__ w, short* __restrict__ wb) {
    int c = blockIdx.x * 4 + (threadIdx.x >> 6);   // 4 waves, one row each
    int lane = threadIdx.x & 63;
    const float4* p = (const float4*)(w + (size_t)c * D_S);
    float4 a = p[lane];
    float4 b = p[lane + 64];
    float ss = a.x * a.x + a.y * a.y + a.z * a.z + a.w * a.w
             + b.x * b.x + b.y * b.y + b.z * b.z + b.w * b.w;
    #pragma unroll
    for (int m = 1; m < 64; m <<= 1) ss += __shfl_xor(ss, m);
    float sc = 1.0f / fmaxf(sqrtf(ss), 1e-12f);
    short4 o1, o2;
    o1.x = f2bf(a.x * sc); o1.y = f2bf(a.y * sc);
    o1.z = f2bf(a.z * sc); o1.w = f2bf(a.w * sc);
    o2.x = f2bf(b.x * sc); o2.y = f2bf(b.y * sc);
    o2.z = f2bf(b.z * sc); o2.w = f2bf(b.w * sc);
    *(short4*)(wb + (size_t)c * D_S + lane * 4) = o1;
    *(short4*)(wb + (size_t)c * D_S + 256 + lane * 4) = o2;
}

// ---------------- kernel 2 (fallback): w row inverse norms ----------------
__global__ void wnorm_k(const float* __restrict__ w, float* __restrict__ winv) {
    int c = blockIdx.x * 4 + (threadIdx.x >> 6);
    int lane = threadIdx.x & 63;
    const float4* p = (const float4*)(w + (size_t)c * D_S);
    float4 a = p[lane];
    float4 b = p[lane + 64];
    float ss = a.x * a.x + a.y * a.y + a.z * a.z + a.w * a.w
             + b.x * b.x + b.y * b.y + b.z * b.z + b.w * b.w;
    #pragma unroll
    for (int m = 1; m < 64; m <<= 1) ss += __shfl_xor(ss, m);
    if (lane == 0) winv[c] = 1.0f / fmaxf(sqrtf(ss), 1e-12f);
}

// ======== shared epilogue: ArcFace transform + per-row softmax partials ========
__device__ __forceinline__ void arc_epilogue(f32x4 acc[4][4], const int* tgts,
                                             int row0, int col0, int cb,
                                             int wm, int wn, int lane,
                                             float* partM, float* partS,
                                             float* tgtlogit) {
    int lg  = lane >> 4;
    int l15 = lane & 15;
    #pragma unroll
    for (int mr = 0; mr < 4; mr++) {
        #pragma unroll
        for (int r = 0; r < 4; r++) {
            int row_l = wm * 64 + mr * 16 + lg * 4 + r;
            int row_g = row0 + row_l;
            int tg = tgts[row_l];
            float lv[4];
            #pragma unroll
            for (int nc = 0; nc < 4; nc++) {
                int c_g = col0 + wn * 64 + nc * 16 + l15;
                float cosv = acc[mr][nc][r];
                cosv = fminf(fmaxf(cosv, -1.0f + EPSV), 1.0f - EPSV);
                float lo = cosv * SCALEF;
                if (c_g == tg) {
                    float s2 = 1.0f - cosv * cosv;
                    s2 = fminf(fmaxf(s2, -1.0f + EPSV), 1.0f - EPSV);
                    float sine = sqrtf(s2);
                    float phi = cosv * COS_M - sine * SIN_M;
                    if (!(cosv > TH_C)) phi = cosv - MM_C;
                    lo = phi * SCALEF;
                    tgtlogit[row_g] = lo;
                }
                if (c_g >= C_S) lo = -INFINITY;
                lv[nc] = lo;
            }
            float m = fmaxf(fmaxf(lv[0], lv[1]), fmaxf(lv[2], lv[3]));
            #pragma unroll
            for (int d = 1; d < 16; d <<= 1) m = fmaxf(m, __shfl_xor(m, d));
            float s = 0.0f;
            #pragma unroll
            for (int nc = 0; nc < 4; nc++)
                if (lv[nc] > -INFINITY) s += __expf(lv[nc] - m);
            #pragma unroll
            for (int d = 1; d < 16; d <<= 1) s += __shfl_xor(s, d);
            if (l15 == 0) {
                int pi = row_g * PPR + cb * 2 + wn;
                partM[pi] = m;
                partS[pi] = s;
            }
        }
    }
}

// ---------------- kernel 3 (fast): bf16 GEMM via global_load_lds + swizzle ----
__global__ void gemm2_k(const short* __restrict__ xb,
                        const short* __restrict__ wb,
                        const int* __restrict__ tgt,
                        float* __restrict__ partM,
                        float* __restrict__ partS,
                        float* __restrict__ tgtlogit) {
    __shared__ short Alds[BM * BK];   // 16 KB, linear dest, XOR-swizzled content
    __shared__ short Blds[BC * BK];   // 16 KB
    __shared__ int tgts[BM];

    // bijective XCD-chunked swizzle: all 4 row-blocks of a w-panel share an XCD
    int orig = blockIdx.x;
    int swz  = (orig & 7) * CHUNK + (orig >> 3);
    int rb = swz & 3, cb = swz >> 2;
    int row0 = rb * BM, col0 = cb * BC;
    int tid = threadIdx.x, wid = tid >> 6, lane = tid & 63;
    int wm = wid >> 1, wn = wid & 1;

    if (tid < BM) tgts[tid] = tgt[row0 + tid];

    f32x4 acc[4][4] = {};

    // staging source coords. LDS linear byte L = (p*4+wid)*1024 + lane*16 holds
    // row r=L>>7, physical slot s=(L>>4)&7; logical k-slot = s ^ (r&7).
    // Note (r&7) == lane>>3, so the inverse-swizzled k-slot is p-independent.
    int lr    = lane >> 3;               // row within 8-row chunk
    int kslot = (lane & 7) ^ lr;         // logical k-slot to fetch (8 elems each)
    const short* aS[4];
    const short* bS[4];
    #pragma unroll
    for (int p = 0; p < 4; p++) {
        int rloc = (p * 4 + wid) * 8 + lr;
        aS[p] = xb + (size_t)(row0 + rloc) * D_S + kslot * 8;
        int cg = col0 + rloc;
        if (cg >= C_S) cg = C_S - 1;     // clamp; epilogue masks c>=C_S
        bS[p] = wb + (size_t)cg * D_S + kslot * 8;
    }

    int l15 = lane & 15, lg = lane >> 4;

    for (int kt = 0; kt < D_S; kt += BK) {
        __syncthreads();
        #pragma unroll
        for (int p = 0; p < 4; p++) {
            GLOAD_LDS16(aS[p] + kt, (char*)Alds + (p * 4 + wid) * 1024);
            GLOAD_LDS16(bS[p] + kt, (char*)Blds + (p * 4 + wid) * 1024);
        }
        __syncthreads();
        #pragma unroll
        for (int kk = 0; kk < BK; kk += 32) {
            int slot = (kk >> 3) + lg;   // logical k-slot for this fragment
            bf16x8 af[4], bfr[4];
            #pragma unroll
            for (int mr = 0; mr < 4; mr++) {
                int r = wm * 64 + mr * 16 + l15;
                af[mr] = *(const bf16x8*)((char*)Alds + r * 128 +
                                          ((slot ^ (r & 7)) << 4));
            }
            #pragma unroll
            for (int nc = 0; nc < 4; nc++) {
                int c = wn * 64 + nc * 16 + l15;
                bfr[nc] = *(const bf16x8*)((char*)Blds + c * 128 +
                                           ((slot ^ (c & 7)) << 4));
            }
            #pragma unroll
            for (int mr = 0; mr < 4; mr++)
                #pragma unroll
                for (int nc = 0; nc < 4; nc++)
                    acc[mr][nc] = __builtin_amdgcn_mfma_f32_16x16x32_bf16(
                        af[mr], bfr[nc], acc[mr][nc], 0, 0, 0);
        }
    }

    arc_epilogue(acc, tgts, row0, col0, cb, wm, wn, lane, partM, partS, tgtlogit);
}

// ---------------- kernel 3 (fallback): round-2 verified GEMM ----------------
__global__ void gemm_arc_k(const short* __restrict__ xb,
                           const float* __restrict__ w,
                           const float* __restrict__ winv,
                           const int* __restrict__ tgt,
                           float* __restrict__ partM,
                           float* __restrict__ partS,
                           float* __restrict__ tgtlogit) {
    __shared__ short Alds[BM * BK];
    __shared__ short Blds[BC * BK];
    __shared__ int tgts[BM];

    int rb = blockIdx.x;
    int cb = blockIdx.y;
    int row0 = rb * BM;
    int col0 = cb * BC;
    int tid = threadIdx.x;
    int wid = tid >> 6;
    int lane = tid & 63;
    int wm = wid >> 1;
    int wn = wid & 1;

    if (tid < BM) tgts[tid] = tgt[row0 + tid];

    f32x4 acc[4][4] = {};

    int bc_r = tid >> 1;
    int bkh  = (tid & 1) * 32;
    int cg   = col0 + bc_r;
    int csrc = cg < C_S ? cg : C_S - 1;
    float wi = winv[csrc];

    for (int kt = 0; kt < D_S; kt += BK) {
        __syncthreads();
        #pragma unroll
        for (int p = 0; p < 4; p++) {
            int flat = p * 4096 + tid * 16;
            int m  = flat >> 7;
            int kb = (flat & 127) >> 1;
            *(int4*)((char*)Alds + flat) =
                *(const int4*)(xb + (size_t)(row0 + m) * D_S + kt + kb);
        }
        {
            const float4* wp = (const float4*)(w + (size_t)csrc * D_S + kt + bkh);
            char* bdst = (char*)Blds + bc_r * 128 + bkh * 2;
            #pragma unroll
            for (int j = 0; j < 8; j++) {
                float4 v = wp[j];
                short4 o;
                o.x = f2bf(v.x * wi);
                o.y = f2bf(v.y * wi);
                o.z = f2bf(v.z * wi);
                o.w = f2bf(v.w * wi);
                *(short4*)(bdst + j * 8) = o;
            }
        }
        __syncthreads();
        #pragma unroll
        for (int kk = 0; kk < BK; kk += 32) {
            int krow = kk + ((lane >> 4) << 3);
            bf16x8 af[4], bfr[4];
            #pragma unroll
            for (int mr = 0; mr < 4; mr++) {
                int r = wm * 64 + mr * 16 + (lane & 15);
                af[mr] = *(const bf16x8*)((char*)Alds + r * 128 + krow * 2);
            }
            #pragma unroll
            for (int nc = 0; nc < 4; nc++) {
                int c = wn * 64 + nc * 16 + (lane & 15);
                bfr[nc] = *(const bf16x8*)((char*)Blds + c * 128 + krow * 2);
            }
            #pragma unroll
            for (int mr = 0; mr < 4; mr++)
                #pragma unroll
                for (int nc = 0; nc < 4; nc++)
                    acc[mr][nc] = __builtin_amdgcn_mfma_f32_16x16x32_bf16(
                        af[mr], bfr[nc], acc[mr][nc], 0, 0, 0);
        }
    }

    arc_epilogue(acc, tgts, row0, col0, cb, wm, wn, lane, partM, partS, tgtlogit);
}

// ---------------- kernel 4: per-row merge of partials -> nll ----------------
__global__ void reduce_k(const float* __restrict__ partM,
                         const float* __restrict__ partS,
                         const float* __restrict__ tgtlogit,
                         float* __restrict__ nll) {
    int row = blockIdx.x;
    int tid = threadIdx.x;
    float m = -INFINITY, s = 0.0f;
    for (int p = tid; p < PPR; p += 256) {
        float mp = partM[(size_t)row * PPR + p];
        float sp = partS[(size_t)row * PPR + p];
        if (sp > 0.0f) {
            float mn = fmaxf(m, mp);
            s = s * __expf(m - mn) + sp * __expf(mp - mn);
            m = mn;
        }
    }
    __shared__ float rm[256], rs[256];
    rm[tid] = m; rs[tid] = s;
    __syncthreads();
    for (int h = 128; h > 0; h >>= 1) {
        if (tid < h) {
            float mp = rm[tid + h], sp = rs[tid + h];
            if (sp > 0.0f) {
                float mn = fmaxf(rm[tid], mp);
                rs[tid] = rs[tid] * __expf(rm[tid] - mn) + sp * __expf(mp - mn);
                rm[tid] = mn;
            }
        }
        __syncthreads();
    }
    if (tid == 0) nll[row] = (rm[0] + logf(rs[0])) - tgtlogit[row];
}

// ---------------- kernel 5: mean ----------------
__global__ void finalize_k(const float* __restrict__ nll, float* __restrict__ out) {
    int tid = threadIdx.x;
    float v = nll[tid] + nll[tid + 256];
    #pragma unroll
    for (int d = 1; d < 64; d <<= 1) v += __shfl_xor(v, d);
    __shared__ float sr[4];
    if ((tid & 63) == 0) sr[tid >> 6] = v;
    __syncthreads();
    if (tid == 0) out[0] = (sr[0] + sr[1] + sr[2] + sr[3]) * (1.0f / 512.0f);
}

extern "C" void kernel_launch(void* const* d_in, const int* in_sizes, int n_in,
                              void* d_out, int out_size, void* d_ws, size_t ws_size,
                              hipStream_t stream) {
    const float* x   = (const float*)d_in[0];
    const int*   tgt = (const int*)d_in[1];
    const float* w   = (const float*)d_in[2];
    float* out = (float*)d_out;
    char* ws = (char*)d_ws;

    // fast-path layout
    short* xb  = (short*)(ws + 0);             // 524288
    float* tgl = (float*)(ws + 524288);        // 2048
    float* nll = (float*)(ws + 526336);        // 2048
    float* pM  = (float*)(ws + 528384);        // 3203072
    float* pS  = (float*)(ws + 3731456);       // 3203072
    short* wb  = (short*)(ws + 6934528);       // 102400000 -> end 109334528

    if (ws_size >= 109334528ULL) {
        xnorm_k<<<512, 256, 0, stream>>>(x, xb);
        wnc_k<<<C_S / 4, 256, 0, stream>>>(w, wb);
        gemm2_k<<<NWG, 256, 0, stream>>>(xb, wb, tgt, pM, pS, tgl);
        reduce_k<<<512, 256, 0, stream>>>(pM, pS, tgl, nll);
        finalize_k<<<1, 256, 0, stream>>>(nll, out);
    } else {
        // fallback layout (round-2 verified path)
        float* winv = (float*)(ws + 524288);
        float* tglf = (float*)(ws + 924288);
        float* nllf = (float*)(ws + 926336);
        float* pMf  = (float*)(ws + 928384);
        float* pSf  = (float*)(ws + 4131456);
        xnorm_k<<<512, 256, 0, stream>>>(x, xb);
        wnorm_k<<<C_S / 4, 256, 0, stream>>>(w, winv);
        dim3 g(4, NCB);
        gemm_arc_k<<<g, 256, 0, stream>>>(xb, w, winv, tgt, pMf, pSf, tglf);
        reduce_k<<<512, 256, 0, stream>>>(pMf, pSf, tglf, nllf);
        finalize_k<<<1, 256, 0, stream>>>(nllf, out);
    }
}